// Round 11
// baseline (393.548 us; speedup 1.0000x reference)
//
#include <hip/hip_runtime.h>
#include <stdint.h>

typedef __attribute__((ext_vector_type(8))) short bf16x8;
typedef __attribute__((ext_vector_type(4))) float f32x4;

#define MFMA16(a, b, c) __builtin_amdgcn_mfma_f32_16x16x32_bf16(a, b, c, 0, 0, 0)
#define VNEG (-1e30f)

constexpr int B_ = 8, S_ = 16, P_ = 256, Q_ = 96, D_ = 768;
constexpr int OUTW = 4 * D_;          // 3072

// ws layout (bytes)
constexpr size_t WS_TU  = 0;                         // [B][Q] f32        3072
constexpr size_t WS_M   = 4096;                      // [BS][P] f32       131072
constexpr size_t WS_BHI = 135168;                    // [B][24][6][64][8] bf16 (B' frags)
constexpr size_t WS_UHI = WS_BHI + 1179648;          // [B][48][3][64][8] bf16 (u^T frags)
constexpr size_t WS_CNT = WS_UHI + 1179648;          // [BS] int counters (zeroed by prolog)

__device__ __forceinline__ short f2bf(float f) {
    unsigned u = __builtin_bit_cast(unsigned, f);
    u += 0x7FFFu + ((u >> 16) & 1u);
    return (short)(u >> 16);
}
__device__ __forceinline__ float bf2f(short s) {
    return __builtin_bit_cast(float, ((unsigned)(unsigned short)s) << 16);
}

// ---------------- K0 (fused prolog): tu | B'-frags | u^T-frags | zero cnt ----------------
__global__ __launch_bounds__(256) void k_prolog(const float* __restrict__ u,
                                                const float* __restrict__ umask,
                                                const float* __restrict__ wv,
                                                const float* __restrict__ bsc,
                                                float* __restrict__ tu,
                                                short* __restrict__ bhi,
                                                short* __restrict__ uhi,
                                                int* __restrict__ cnt) {
    int blk = blockIdx.x;
    if (blk < 192) {
        if (blk == 0 && threadIdx.x < 128) cnt[threadIdx.x] = 0;   // reset handshake counters
        int gw = (blk * 256 + threadIdx.x) >> 6;      // 0..767
        int l  = threadIdx.x & 63;
        const float* up = u + (size_t)gw * D_;
        const float* wu = wv + D_;
        float s = 0.f;
        #pragma unroll
        for (int i = 0; i < D_ / 64; ++i) s += up[i * 64 + l] * wu[i * 64 + l];
        #pragma unroll
        for (int off = 32; off; off >>= 1) s += __shfl_xor(s, off, 64);
        if (l == 0) tu[gw] = s + bsc[0] + (1.f - umask[gw]) * VNEG;
    } else if (blk < 2496) {
        // B'[b][d][q] = w_h[d]+w_hu[d]*u[b][q][d]
        // idx: ((b*24+ks)*6+nt)*512 + l*8 + j ; q=nt*16+(l&15), d=ks*32+(l>>4)*8+j
        int t = (blk - 192) * 256 + threadIdx.x;      // 0 .. 589823
        int j = t & 7, l = (t >> 3) & 63;
        int rest = t >> 9;
        int nt = rest % 6; rest /= 6;
        int ks = rest % 24; int b = rest / 24;
        int q = nt * 16 + (l & 15);
        int d = ks * 32 + (l >> 4) * 8 + j;
        float val = wv[d] + wv[2 * D_ + d] * u[((size_t)b * Q_ + q) * D_ + d];
        bhi[t] = f2bf(val);
    } else {
        // u^T[d][q] frags: ((b*48+dt)*3+ks)*512 + l*8 + j ; d=dt*16+(l&15), q=ks*32+(l>>4)*8+j
        int t = (blk - 2496) * 256 + threadIdx.x;     // 0 .. 589823
        int j = t & 7, l = (t >> 3) & 63;
        int rest = t >> 9;
        int ks = rest % 3; rest /= 3;
        int dt = rest % 48; int b = rest / 48;
        int d = dt * 16 + (l & 15);
        int q = ks * 32 + (l >> 4) * 8 + j;
        uhi[t] = f2bf(u[((size_t)b * Q_ + q) * D_ + d]);
    }
}

// ---------------- K1 (fused): R5 k_main + per-bs handshake + quarter-tail ----------------
// 512 blocks x 512 threads, 2 blocks/CU => ALL 512 co-resident (spin is deadlock-free).
// Main phase identical to R5 (163.7us best). Tail: the 4 pt-siblings of each bs
// sync via release/acquire atomic counter, then each does 3 of the 12 d-chunks
// of the former k_post (q2c softmax + g0/g3), with h L2/L3-warm.
__global__ __launch_bounds__(512, 4) void k_main(const float* __restrict__ h,
                                                 const float* __restrict__ hmask,
                                                 const float* __restrict__ tu,
                                                 const short* __restrict__ bhi,
                                                 const short* __restrict__ uhi,
                                                 float* __restrict__ out,
                                                 float* __restrict__ mws,
                                                 int* __restrict__ cnt) {
    __shared__ float cbuf[4][16][100];   // per row-group logits/P (pad 96->100)
    __shared__ float q2cS[256];
    __shared__ float redS[8];
    __shared__ f32x4 partS[32][16];
    __shared__ float haS[64];

    // XCD swizzle: b = bid&7 so each XCD's L2 caches one b's fragment set
    int bid = blockIdx.x;                // 512
    int b   = bid & 7;
    int s_  = (bid >> 3) & 15;
    int pt  = bid >> 7;                  // 0..3
    int bs  = (b << 4) | s_;

    int tid = threadIdx.x;
    int wv = tid >> 6;                   // 0..7
    int gidx = wv >> 1;                  // row-group 0..3
    int hk = wv & 1;                     // half 0/1
    int l = tid & 63;
    int l15 = l & 15, g = l >> 4;
    int prow0 = pt * 64 + gidx * 16;     // group's first p within (b,s)

    const float* hrow = h + ((size_t)bs * P_ + prow0 + l15) * D_;

    // ---- partial logits = h @ B' over this wave's K-half (1-term bf16 B) ----
    f32x4 acc[6];
    #pragma unroll
    for (int i = 0; i < 6; ++i) acc[i] = (f32x4){0.f, 0.f, 0.f, 0.f};

    const short* bhp = bhi + (size_t)b * (24 * 6 * 512) + l * 8;

    int ks0 = hk * 12;
    #pragma unroll 3
    for (int ki = 0; ki < 12; ++ki) {
        int ks = ks0 + ki;
        const float* ap = hrow + ks * 32 + g * 8;
        f32x4 a0 = *(const f32x4*)ap;
        f32x4 a1 = *(const f32x4*)(ap + 4);
        bf16x8 ah;
        #pragma unroll
        for (int j = 0; j < 4; ++j) { ah[j] = f2bf(a0[j]); ah[4 + j] = f2bf(a1[j]); }
        #pragma unroll
        for (int nt = 0; nt < 6; ++nt) {
            bf16x8 bh = *(const bf16x8*)(bhp + (ks * 6 + nt) * 512);
            acc[nt] = MFMA16(ah, bh, acc[nt]);
        }
    }

    // ---- combine K-halves in LDS (C/D layout: row=g*4+r, col=nt*16+l15) ----
    if (hk == 0) {
        #pragma unroll
        for (int r = 0; r < 4; ++r)
            #pragma unroll
            for (int nt = 0; nt < 6; ++nt)
                cbuf[gidx][g * 4 + r][nt * 16 + l15] = acc[nt][r];
    }
    __syncthreads();
    if (hk == 1) {
        #pragma unroll
        for (int r = 0; r < 4; ++r)
            #pragma unroll
            for (int nt = 0; nt < 6; ++nt)
                cbuf[gidx][g * 4 + r][nt * 16 + l15] += acc[nt][r];
    }
    __syncthreads();

    // ---- rank-1 terms + softmax over q, 8 rows per wave (8-lane groups) ----
    {
        int row8 = hk * 8 + (l >> 3);    // wave's row within group
        int qb = l & 7;
        int prow = prow0 + row8;
        float hmv = (1.f - hmask[(size_t)bs * P_ + prow]) * VNEG;
        float v[12];
        float mx = -1e38f;
        #pragma unroll
        for (int k = 0; k < 12; ++k) {
            int q = qb + 8 * k;
            v[k] = cbuf[gidx][row8][q] + tu[b * Q_ + q] + hmv;
            mx = fmaxf(mx, v[k]);
        }
        #pragma unroll
        for (int off = 1; off < 8; off <<= 1) mx = fmaxf(mx, __shfl_xor(mx, off, 64));
        float sum = 0.f;
        #pragma unroll
        for (int k = 0; k < 12; ++k) {
            float e = __expf(v[k] - mx);
            v[k] = e;
            sum += e;
        }
        #pragma unroll
        for (int off = 1; off < 8; off <<= 1) sum += __shfl_xor(sum, off, 64);
        float inv = 1.f / sum;
        if (qb == 0) mws[(size_t)bs * P_ + prow] = mx;
        #pragma unroll
        for (int k = 0; k < 12; ++k)
            cbuf[gidx][row8][qb + 8 * k] = v[k] * inv;
    }
    __syncthreads();

    // ---- build C^T frags hi+lo from exact f32 P in LDS ----
    bf16x8 chi[3], clo[3];
    #pragma unroll
    for (int ks = 0; ks < 3; ++ks) {
        const float* cp = &cbuf[gidx][l15][ks * 32 + g * 8];
        #pragma unroll
        for (int j = 0; j < 8; ++j) {
            float v = cp[j];
            short hi = f2bf(v);
            chi[ks][j] = hi;
            clo[ks][j] = f2bf(v - bf2f(hi));
        }
    }

    // ---- u_a^T = u_hi @ (C_hi + C_lo): A=u-frags (rows=d), B=C-frags (cols=p) ----
    const short* uhp = uhi + (size_t)b * (48 * 3 * 512) + l * 8;

    int p = prow0 + l15;
    size_t rowoff = ((size_t)bs * P_ + p) * OUTW;
    const float* hrow2 = h + ((size_t)bs * P_ + p) * D_;

    for (int nci = 0; nci < 3; ++nci) {
        int nc = hk * 3 + nci;
        f32x4 ua[8];
        #pragma unroll
        for (int i = 0; i < 8; ++i) ua[i] = (f32x4){0.f, 0.f, 0.f, 0.f};
        #pragma unroll
        for (int ks = 0; ks < 3; ++ks) {
            #pragma unroll
            for (int i = 0; i < 8; ++i) {
                int dt = nc * 8 + i;
                bf16x8 uh = *(const bf16x8*)(uhp + (dt * 3 + ks) * 512);
                ua[i] = MFMA16(uh, chi[ks], ua[i]);
                ua[i] = MFMA16(uh, clo[ks], ua[i]);
            }
        }
        #pragma unroll
        for (int i = 0; i < 8; ++i) {
            int d0 = (nc * 8 + i) * 16 + g * 4;      // lane holds d0..d0+3 (consecutive)
            f32x4 hv = *(const f32x4*)(hrow2 + d0);
            f32x4 g2v = hv * ua[i];
            *(f32x4*)(out + rowoff + D_ + d0) = ua[i];       // g1 = u_a
            *(f32x4*)(out + rowoff + 2 * D_ + d0) = g2v;     // g2 = h*u_a
        }
    }

    // ---- handshake: wait for all 4 pt-siblings of this bs (m complete) ----
    __threadfence();
    if (tid == 0) {
        __hip_atomic_fetch_add(&cnt[bs], 1, __ATOMIC_RELEASE, __HIP_MEMORY_SCOPE_AGENT);
        while (__hip_atomic_load(&cnt[bs], __ATOMIC_ACQUIRE, __HIP_MEMORY_SCOPE_AGENT) < 4)
            __builtin_amdgcn_s_sleep(2);
    }
    __syncthreads();

    // ---- tail part 1: q2c = softmax_p(m) (tid<256; k_post verbatim) ----
    if (tid < 256) {
        int w2 = tid >> 6;
        float mv = mws[(size_t)bs * P_ + tid];
        float mx = mv;
        #pragma unroll
        for (int off = 32; off; off >>= 1) mx = fmaxf(mx, __shfl_xor(mx, off, 64));
        if ((tid & 63) == 0) redS[w2] = mx;
    }
    __syncthreads();
    if (tid < 256) {
        float mx = fmaxf(fmaxf(redS[0], redS[1]), fmaxf(redS[2], redS[3]));
        float mv = mws[(size_t)bs * P_ + tid];
        float e = __expf(mv - mx);
        float sm = e;
        #pragma unroll
        for (int off = 32; off; off >>= 1) sm += __shfl_xor(sm, off, 64);
        if ((tid & 63) == 0) redS[4 + (tid >> 6)] = sm;
        q2cS[tid] = e;           // un-normalized; divide after sum known
    }
    __syncthreads();
    {
        float smAll = redS[4] + redS[5] + redS[6] + redS[7];
        if (tid < 256) q2cS[tid] = q2cS[tid] / smAll;
    }
    __syncthreads();

    // ---- tail part 2: this block's 3 d-chunks of g0 = h, g3 = h*h_a ----
    int c = tid & 15, r = tid >> 4;          // c: d-quad 0..15, r: p-group 0..31
    const float* hb = h   + (size_t)bs * P_ * D_ + c * 4;
    float*       ob = out + (size_t)bs * P_ * OUTW + c * 4;
    for (int cc = 0; cc < 3; ++cc) {
        int d0 = (pt * 3 + cc) * 64;
        f32x4 a2 = (f32x4){0.f, 0.f, 0.f, 0.f};
        #pragma unroll
        for (int k = 0; k < 8; ++k) {
            int pp = r + k * 32;
            f32x4 hv = *(const f32x4*)(hb + (size_t)pp * D_ + d0);
            a2 += q2cS[pp] * hv;
        }
        partS[r][c] = a2;
        __syncthreads();
        if (tid < 64) {
            float sv = 0.f;
            #pragma unroll
            for (int rr = 0; rr < 32; ++rr) sv += partS[rr][tid >> 2][tid & 3];
            haS[tid] = sv;
        }
        __syncthreads();
        f32x4 hav = *(const f32x4*)&haS[c * 4];
        #pragma unroll
        for (int k = 0; k < 8; ++k) {
            int pp = r + k * 32;
            f32x4 hv = *(const f32x4*)(hb + (size_t)pp * D_ + d0);   // L1/L2-hot re-read
            *(f32x4*)(ob + (size_t)pp * OUTW + d0) = hv;             // g0
            f32x4 g3 = hv * hav;
            *(f32x4*)(ob + (size_t)pp * OUTW + d0 + 3 * D_) = g3;    // g3
        }
        __syncthreads();   // partS/haS reuse
    }
}

extern "C" void kernel_launch(void* const* d_in, const int* in_sizes, int n_in,
                              void* d_out, int out_size, void* d_ws, size_t ws_size,
                              hipStream_t stream) {
    const float* h     = (const float*)d_in[0];
    const float* u     = (const float*)d_in[1];
    const float* hmask = (const float*)d_in[2];
    const float* umask = (const float*)d_in[3];
    // d_in[4] = is_train (unused)
    const float* wv    = (const float*)d_in[5];
    const float* bsc   = (const float*)d_in[6];
    float* out = (float*)d_out;

    char* ws = (char*)d_ws;
    float* tu  = (float*)(ws + WS_TU);
    float* mws = (float*)(ws + WS_M);
    short* bhi = (short*)(ws + WS_BHI);
    short* uhi = (short*)(ws + WS_UHI);
    int*   cnt = (int*)(ws + WS_CNT);

    k_prolog<<<4800, 256, 0, stream>>>(u, umask, wv, bsc, tu, bhi, uhi, cnt);
    k_main<<<512, 512, 0, stream>>>(h, hmask, tu, bhi, uhi, out, mws, cnt);
}

// Round 12
// 148.932 us; speedup vs baseline: 2.6425x; 2.6425x over previous
//
#include <hip/hip_runtime.h>
#include <stdint.h>

typedef __attribute__((ext_vector_type(8))) short bf16x8;
typedef __attribute__((ext_vector_type(4))) float f32x4;

#define MFMA16(a, b, c) __builtin_amdgcn_mfma_f32_16x16x32_bf16(a, b, c, 0, 0, 0)
#define VNEG (-1e30f)
#define NTSTORE(p, v) __builtin_nontemporal_store((v), (f32x4*)(p))

constexpr int B_ = 8, S_ = 16, P_ = 256, Q_ = 96, D_ = 768;
constexpr int OUTW = 4 * D_;          // 3072

// ws layout (bytes)
constexpr size_t WS_TU  = 0;                         // [B][Q] f32        3072
constexpr size_t WS_M   = 4096;                      // [BS][P] f32       131072
constexpr size_t WS_BHI = 135168;                    // [B][24][6][64][8] bf16 (B' frags)
constexpr size_t WS_UHI = WS_BHI + 1179648;          // [B][48][3][64][8] bf16 (u^T frags)

__device__ __forceinline__ short f2bf(float f) {
    unsigned u = __builtin_bit_cast(unsigned, f);
    u += 0x7FFFu + ((u >> 16) & 1u);
    return (short)(u >> 16);
}
__device__ __forceinline__ float bf2f(short s) {
    return __builtin_bit_cast(float, ((unsigned)(unsigned short)s) << 16);
}

// ---------------- K0 (fused prolog): tu | B'-frags | u^T-frags ----------------
__global__ __launch_bounds__(256) void k_prolog(const float* __restrict__ u,
                                                const float* __restrict__ umask,
                                                const float* __restrict__ wv,
                                                const float* __restrict__ bsc,
                                                float* __restrict__ tu,
                                                short* __restrict__ bhi,
                                                short* __restrict__ uhi) {
    int blk = blockIdx.x;
    if (blk < 192) {
        int gw = (blk * 256 + threadIdx.x) >> 6;      // 0..767
        int l  = threadIdx.x & 63;
        const float* up = u + (size_t)gw * D_;
        const float* wu = wv + D_;
        float s = 0.f;
        #pragma unroll
        for (int i = 0; i < D_ / 64; ++i) s += up[i * 64 + l] * wu[i * 64 + l];
        #pragma unroll
        for (int off = 32; off; off >>= 1) s += __shfl_xor(s, off, 64);
        if (l == 0) tu[gw] = s + bsc[0] + (1.f - umask[gw]) * VNEG;
    } else if (blk < 2496) {
        // B'[b][d][q] = w_h[d]+w_hu[d]*u[b][q][d]
        // idx: ((b*24+ks)*6+nt)*512 + l*8 + j ; q=nt*16+(l&15), d=ks*32+(l>>4)*8+j
        int t = (blk - 192) * 256 + threadIdx.x;      // 0 .. 589823
        int j = t & 7, l = (t >> 3) & 63;
        int rest = t >> 9;
        int nt = rest % 6; rest /= 6;
        int ks = rest % 24; int b = rest / 24;
        int q = nt * 16 + (l & 15);
        int d = ks * 32 + (l >> 4) * 8 + j;
        float val = wv[d] + wv[2 * D_ + d] * u[((size_t)b * Q_ + q) * D_ + d];
        bhi[t] = f2bf(val);
    } else {
        // u^T[d][q] frags: ((b*48+dt)*3+ks)*512 + l*8 + j ; d=dt*16+(l&15), q=ks*32+(l>>4)*8+j
        int t = (blk - 2496) * 256 + threadIdx.x;     // 0 .. 589823
        int j = t & 7, l = (t >> 3) & 63;
        int rest = t >> 9;
        int ks = rest % 3; rest /= 3;
        int dt = rest % 48; int b = rest / 48;
        int d = dt * 16 + (l & 15);
        int q = ks * 32 + (l >> 4) * 8 + j;
        uhi[t] = f2bf(u[((size_t)b * Q_ + q) * D_ + d]);
    }
}

// ---------------- K1 (R5 + NT stores): logits -> softmax(q) -> u_a^T ; g1,g2,m ----------------
__global__ __launch_bounds__(512, 4) void k_main(const float* __restrict__ h,
                                                 const float* __restrict__ hmask,
                                                 const float* __restrict__ tu,
                                                 const short* __restrict__ bhi,
                                                 const short* __restrict__ uhi,
                                                 float* __restrict__ out,
                                                 float* __restrict__ mws) {
    __shared__ float cbuf[4][16][100];   // per row-group logits/P (pad 96->100)

    // XCD swizzle: b = bid&7 so each XCD's L2 caches one b's fragment set
    int bid = blockIdx.x;                // 512
    int b   = bid & 7;
    int s_  = (bid >> 3) & 15;
    int pt  = bid >> 7;                  // 0..3
    int bs  = (b << 4) | s_;

    int tid = threadIdx.x;
    int wv = tid >> 6;                   // 0..7
    int gidx = wv >> 1;                  // row-group 0..3
    int hk = wv & 1;                     // half 0/1
    int l = tid & 63;
    int l15 = l & 15, g = l >> 4;
    int prow0 = pt * 64 + gidx * 16;     // group's first p within (b,s)

    const float* hrow = h + ((size_t)bs * P_ + prow0 + l15) * D_;

    // ---- partial logits = h @ B' over this wave's K-half (1-term bf16 B) ----
    f32x4 acc[6];
    #pragma unroll
    for (int i = 0; i < 6; ++i) acc[i] = (f32x4){0.f, 0.f, 0.f, 0.f};

    const short* bhp = bhi + (size_t)b * (24 * 6 * 512) + l * 8;

    int ks0 = hk * 12;
    #pragma unroll 3
    for (int ki = 0; ki < 12; ++ki) {
        int ks = ks0 + ki;
        const float* ap = hrow + ks * 32 + g * 8;
        f32x4 a0 = *(const f32x4*)ap;
        f32x4 a1 = *(const f32x4*)(ap + 4);
        bf16x8 ah;
        #pragma unroll
        for (int j = 0; j < 4; ++j) { ah[j] = f2bf(a0[j]); ah[4 + j] = f2bf(a1[j]); }
        #pragma unroll
        for (int nt = 0; nt < 6; ++nt) {
            bf16x8 bh = *(const bf16x8*)(bhp + (ks * 6 + nt) * 512);
            acc[nt] = MFMA16(ah, bh, acc[nt]);
        }
    }

    // ---- combine K-halves in LDS (C/D layout: row=g*4+r, col=nt*16+l15) ----
    if (hk == 0) {
        #pragma unroll
        for (int r = 0; r < 4; ++r)
            #pragma unroll
            for (int nt = 0; nt < 6; ++nt)
                cbuf[gidx][g * 4 + r][nt * 16 + l15] = acc[nt][r];
    }
    __syncthreads();
    if (hk == 1) {
        #pragma unroll
        for (int r = 0; r < 4; ++r)
            #pragma unroll
            for (int nt = 0; nt < 6; ++nt)
                cbuf[gidx][g * 4 + r][nt * 16 + l15] += acc[nt][r];
    }
    __syncthreads();

    // ---- rank-1 terms + softmax over q, 8 rows per wave (8-lane groups) ----
    {
        int row8 = hk * 8 + (l >> 3);    // wave's row within group
        int qb = l & 7;
        int prow = prow0 + row8;
        float hmv = (1.f - hmask[(size_t)bs * P_ + prow]) * VNEG;
        float v[12];
        float mx = -1e38f;
        #pragma unroll
        for (int k = 0; k < 12; ++k) {
            int q = qb + 8 * k;
            v[k] = cbuf[gidx][row8][q] + tu[b * Q_ + q] + hmv;
            mx = fmaxf(mx, v[k]);
        }
        #pragma unroll
        for (int off = 1; off < 8; off <<= 1) mx = fmaxf(mx, __shfl_xor(mx, off, 64));
        float sum = 0.f;
        #pragma unroll
        for (int k = 0; k < 12; ++k) {
            float e = __expf(v[k] - mx);
            v[k] = e;
            sum += e;
        }
        #pragma unroll
        for (int off = 1; off < 8; off <<= 1) sum += __shfl_xor(sum, off, 64);
        float inv = 1.f / sum;
        if (qb == 0) mws[(size_t)bs * P_ + prow] = mx;
        #pragma unroll
        for (int k = 0; k < 12; ++k)
            cbuf[gidx][row8][qb + 8 * k] = v[k] * inv;
    }
    __syncthreads();

    // ---- build C^T frags hi+lo from exact f32 P in LDS ----
    bf16x8 chi[3], clo[3];
    #pragma unroll
    for (int ks = 0; ks < 3; ++ks) {
        const float* cp = &cbuf[gidx][l15][ks * 32 + g * 8];
        #pragma unroll
        for (int j = 0; j < 8; ++j) {
            float v = cp[j];
            short hi = f2bf(v);
            chi[ks][j] = hi;
            clo[ks][j] = f2bf(v - bf2f(hi));
        }
    }

    // ---- u_a^T = u_hi @ (C_hi + C_lo): A=u-frags (rows=d), B=C-frags (cols=p) ----
    const short* uhp = uhi + (size_t)b * (48 * 3 * 512) + l * 8;

    int p = prow0 + l15;
    size_t rowoff = ((size_t)bs * P_ + p) * OUTW;
    const float* hrow2 = h + ((size_t)bs * P_ + p) * D_;

    for (int nci = 0; nci < 3; ++nci) {
        int nc = hk * 3 + nci;
        f32x4 ua[8];
        #pragma unroll
        for (int i = 0; i < 8; ++i) ua[i] = (f32x4){0.f, 0.f, 0.f, 0.f};
        #pragma unroll
        for (int ks = 0; ks < 3; ++ks) {
            #pragma unroll
            for (int i = 0; i < 8; ++i) {
                int dt = nc * 8 + i;
                bf16x8 uh = *(const bf16x8*)(uhp + (dt * 3 + ks) * 512);
                ua[i] = MFMA16(uh, chi[ks], ua[i]);
                ua[i] = MFMA16(uh, clo[ks], ua[i]);
            }
        }
        #pragma unroll
        for (int i = 0; i < 8; ++i) {
            int d0 = (nc * 8 + i) * 16 + g * 4;      // lane holds d0..d0+3 (consecutive)
            f32x4 hv = *(const f32x4*)(hrow2 + d0);
            f32x4 g2v = hv * ua[i];
            NTSTORE(out + rowoff + D_ + d0, ua[i]);        // g1 = u_a (never re-read)
            NTSTORE(out + rowoff + 2 * D_ + d0, g2v);      // g2 = h*u_a
        }
    }
}

// ---------------- K2 (R5 + NT stores): q2c softmax over p, h_a; writes g0, g3 ----------------
__global__ __launch_bounds__(256) void k_post(const float* __restrict__ h,
                                              const float* __restrict__ mws,
                                              float* __restrict__ out) {
    __shared__ float q2c[256];
    __shared__ float red[8];
    __shared__ f32x4 part[16][16];
    __shared__ float ha[64];

    int bid = blockIdx.x;                 // 12*128: same-bs blocks 128 apart -> same XCD
    int bs = bid & 127, ch = bid >> 7;
    int d0 = ch * 64;
    int t = threadIdx.x;
    int w = t >> 6, l = t & 63;

    // softmax over p of m
    float mv = mws[(size_t)bs * P_ + t];
    float mx = mv;
    #pragma unroll
    for (int off = 32; off; off >>= 1) mx = fmaxf(mx, __shfl_xor(mx, off, 64));
    if (l == 0) red[w] = mx;
    __syncthreads();
    mx = fmaxf(fmaxf(red[0], red[1]), fmaxf(red[2], red[3]));
    float e = __expf(mv - mx);
    float sm = e;
    #pragma unroll
    for (int off = 32; off; off >>= 1) sm += __shfl_xor(sm, off, 64);
    if (l == 0) red[4 + w] = sm;
    __syncthreads();
    sm = red[4] + red[5] + red[6] + red[7];
    q2c[t] = e / sm;
    __syncthreads();

    // h_a over this 64-wide d chunk; thread = (r=p-group, c=d-quad)
    int c = t & 15, r = t >> 4;
    const float* hb = h + (size_t)bs * P_ * D_ + d0 + c * 4;
    f32x4 acc = (f32x4){0.f, 0.f, 0.f, 0.f};
    #pragma unroll
    for (int k = 0; k < 16; ++k) {
        int p = r + k * 16;
        f32x4 hv = *(const f32x4*)(hb + (size_t)p * D_);
        acc += q2c[p] * hv;
    }
    part[r][c] = acc;
    __syncthreads();
    if (t < 64) {
        float sv = 0.f;
        #pragma unroll
        for (int rr = 0; rr < 16; ++rr) sv += part[rr][t >> 2][t & 3];
        ha[t] = sv;
    }
    __syncthreads();
    f32x4 hav = *(const f32x4*)&ha[c * 4];

    // g0 = h, g3 = h * h_a (both never re-read -> NT stores keep h L3-resident)
    size_t ob = (size_t)bs * P_ * OUTW + d0 + c * 4;
    #pragma unroll
    for (int k = 0; k < 16; ++k) {
        int p = r + k * 16;
        f32x4 hv = *(const f32x4*)(hb + (size_t)p * D_);
        NTSTORE(out + ob + (size_t)p * OUTW, hv);                  // g0
        f32x4 g3 = hv * hav;
        NTSTORE(out + ob + (size_t)p * OUTW + 3 * D_, g3);         // g3
    }
}

extern "C" void kernel_launch(void* const* d_in, const int* in_sizes, int n_in,
                              void* d_out, int out_size, void* d_ws, size_t ws_size,
                              hipStream_t stream) {
    const float* h     = (const float*)d_in[0];
    const float* u     = (const float*)d_in[1];
    const float* hmask = (const float*)d_in[2];
    const float* umask = (const float*)d_in[3];
    // d_in[4] = is_train (unused)
    const float* wv    = (const float*)d_in[5];
    const float* bsc   = (const float*)d_in[6];
    float* out = (float*)d_out;

    char* ws = (char*)d_ws;
    float* tu  = (float*)(ws + WS_TU);
    float* mws = (float*)(ws + WS_M);
    short* bhi = (short*)(ws + WS_BHI);
    short* uhi = (short*)(ws + WS_UHI);

    k_prolog<<<4800, 256, 0, stream>>>(u, umask, wv, bsc, tu, bhi, uhi);
    k_main<<<512, 512, 0, stream>>>(h, hmask, tu, bhi, uhi, out, mws);
    k_post<<<1536, 256, 0, stream>>>(h, mws, out);
}